// Round 1
// baseline (677.686 us; speedup 1.0000x reference)
//
#include <hip/hip_runtime.h>

// Downsampler: depthwise 4x4 conv, stride 4, VALID, kernel shared across channels.
// x: (N=16, C=8, H=1024, W=1024) fp32, kernel: (4,4) fp32
// out: (16, 8, 256, 256) fp32
// Non-overlapping windows -> each input element read exactly once -> pure
// streaming, memory-bound. Target ~90us at 6.3 TB/s achievable HBM BW.

#define FACTOR 4
#define NN 16
#define CC 8
#define HH 1024
#define WW 1024
#define OH (HH / FACTOR)   // 256
#define OW (WW / FACTOR)   // 256

__global__ __launch_bounds__(256) void Downsampler_24421184045082_kernel(
    const float* __restrict__ x,
    const float* __restrict__ k,
    float* __restrict__ out,
    int total)
{
    int idx = blockIdx.x * blockDim.x + threadIdx.x;
    if (idx >= total) return;

    // idx -> (nc, oh, ow); OW=256 (8 bits), OH=256 (8 bits)
    int ow = idx & (OW - 1);
    int oh = (idx >> 8) & (OH - 1);
    int nc = idx >> 16;

    // Kernel weights: uniform address -> scalar loads, L1/L2 cached.
    float k00 = k[0],  k01 = k[1],  k02 = k[2],  k03 = k[3];
    float k10 = k[4],  k11 = k[5],  k12 = k[6],  k13 = k[7];
    float k20 = k[8],  k21 = k[9],  k22 = k[10], k23 = k[11];
    float k30 = k[12], k31 = k[13], k32 = k[14], k33 = k[15];

    const float* xp = x + (((size_t)nc * HH) + (size_t)oh * FACTOR) * WW
                        + (size_t)ow * FACTOR;

    // 4 rows x float4: lane i reads 16B at base + i*16 -> fully coalesced
    float4 r0 = *reinterpret_cast<const float4*>(xp + 0 * WW);
    float4 r1 = *reinterpret_cast<const float4*>(xp + 1 * WW);
    float4 r2 = *reinterpret_cast<const float4*>(xp + 2 * WW);
    float4 r3 = *reinterpret_cast<const float4*>(xp + 3 * WW);

    float acc = r0.x * k00 + r0.y * k01 + r0.z * k02 + r0.w * k03
              + r1.x * k10 + r1.y * k11 + r1.z * k12 + r1.w * k13
              + r2.x * k20 + r2.y * k21 + r2.z * k22 + r2.w * k23
              + r3.x * k30 + r3.y * k31 + r3.z * k32 + r3.w * k33;

    out[idx] = acc;
}

extern "C" void kernel_launch(void* const* d_in, const int* in_sizes, int n_in,
                              void* d_out, int out_size, void* d_ws, size_t ws_size,
                              hipStream_t stream)
{
    const float* x = (const float*)d_in[0];
    const float* k = (const float*)d_in[1];
    float* out = (float*)d_out;

    const int total = NN * CC * OH * OW;  // 8,388,608
    const int block = 256;
    const int grid = (total + block - 1) / block;  // 32768

    Downsampler_24421184045082_kernel<<<grid, block, 0, stream>>>(x, k, out, total);
}

// Round 2
// 658.180 us; speedup vs baseline: 1.0296x; 1.0296x over previous
//
#include <hip/hip_runtime.h>

// Downsampler: depthwise 4x4 conv, stride 4, VALID, shared kernel.
// x: (16,8,1024,1024) fp32 -> out: (16,8,256,256) fp32.
// Non-overlapping windows: pure streaming, memory-bound.
// Roofline: (512+32) MiB @ ~6.3 TB/s ~= 90 us.
//
// R1 changes vs R0:
//  - grid-stride, 2048 blocks (G11): 16 tiles/thread, #pragma unroll 4
//    keeps 16 float4 loads in flight per thread (deep MLP).
//  - nontemporal load/store: zero-reuse streams skip L2/L3 allocate.

#define FACTOR 4
#define NN 16
#define CC 8
#define HH 1024
#define WW 1024
#define OH (HH / FACTOR)   // 256
#define OW (WW / FACTOR)   // 256
#define TOTAL (NN * CC * OH * OW)   // 8,388,608

#define NBLK 2048
#define NTHR 256
#define STRIDE (NBLK * NTHR)        // 524,288
#define NITER (TOTAL / STRIDE)      // 16 exactly, no tail

typedef float f32x4 __attribute__((ext_vector_type(4)));

__global__ __launch_bounds__(NTHR) void Downsampler_24421184045082_kernel(
    const float* __restrict__ x,
    const float* __restrict__ k,
    float* __restrict__ out)
{
    // Uniform weight loads -> scalar path, hoisted out of the loop.
    float kw[16];
#pragma unroll
    for (int i = 0; i < 16; ++i) kw[i] = k[i];

    const int tid = blockIdx.x * NTHR + threadIdx.x;

#pragma unroll 4
    for (int it = 0; it < NITER; ++it) {
        const int idx = tid + it * STRIDE;

        const int ow = idx & (OW - 1);
        const int oh = (idx >> 8) & (OH - 1);
        const int nc = idx >> 16;

        const float* xp = x + ((size_t)(nc * HH + oh * FACTOR)) * WW
                            + (size_t)ow * FACTOR;

        f32x4 r0 = __builtin_nontemporal_load(
            reinterpret_cast<const f32x4*>(xp + 0 * WW));
        f32x4 r1 = __builtin_nontemporal_load(
            reinterpret_cast<const f32x4*>(xp + 1 * WW));
        f32x4 r2 = __builtin_nontemporal_load(
            reinterpret_cast<const f32x4*>(xp + 2 * WW));
        f32x4 r3 = __builtin_nontemporal_load(
            reinterpret_cast<const f32x4*>(xp + 3 * WW));

        float acc = r0.x * kw[0]  + r0.y * kw[1]  + r0.z * kw[2]  + r0.w * kw[3]
                  + r1.x * kw[4]  + r1.y * kw[5]  + r1.z * kw[6]  + r1.w * kw[7]
                  + r2.x * kw[8]  + r2.y * kw[9]  + r2.z * kw[10] + r2.w * kw[11]
                  + r3.x * kw[12] + r3.y * kw[13] + r3.z * kw[14] + r3.w * kw[15];

        __builtin_nontemporal_store(acc, out + idx);
    }
}

extern "C" void kernel_launch(void* const* d_in, const int* in_sizes, int n_in,
                              void* d_out, int out_size, void* d_ws, size_t ws_size,
                              hipStream_t stream)
{
    const float* x = (const float*)d_in[0];
    const float* k = (const float*)d_in[1];
    float* out = (float*)d_out;

    Downsampler_24421184045082_kernel<<<NBLK, NTHR, 0, stream>>>(x, k, out);
}